// Round 2
// baseline (822.916 us; speedup 1.0000x reference)
//
#include <hip/hip_runtime.h>

#define DIM 128
#define META 5000

// Per-node theta: theta[n] = dot(embedding[n, :], params[:, 0])
// One 64-lane wave per node; each lane handles 2 dims (float2), shuffle-reduce.
__global__ void theta_kernel(const float* __restrict__ emb,
                             const float* __restrict__ params,
                             float* __restrict__ theta, int n_nodes) {
    int gid  = blockIdx.x * blockDim.x + threadIdx.x;
    int node = gid >> 6;
    int lane = threadIdx.x & 63;
    if (node >= n_nodes) return;
    const float2 e = *reinterpret_cast<const float2*>(&emb[(size_t)node * DIM + lane * 2]);
    const float2 p = *reinterpret_cast<const float2*>(&params[lane * 2]);
    float v = e.x * p.x + e.y * p.y;
    #pragma unroll
    for (int off = 32; off; off >>= 1) v += __shfl_xor(v, off);
    if (lane == 0) theta[node] = v;
}

// Per-edge scatter: out[row-META, :] += exp(interval * theta[col]) * emb[col, :]
// 32 lanes per edge, one float4 per lane (32*4 = 128 dims).
__global__ void scatter_kernel(const float* __restrict__ interval,
                               const float* __restrict__ emb,
                               const int* __restrict__ row_idx,
                               const int* __restrict__ col_idx,
                               const float* __restrict__ theta,
                               float* __restrict__ out,
                               int n_edges, int author_num) {
    long long gid = (long long)blockIdx.x * blockDim.x + threadIdx.x;
    long long edge = gid >> 5;
    int lane = (int)(gid & 31);
    if (edge >= n_edges) return;

    int r = row_idx[edge];
    int out_r = r - META;
    if (out_r < 0 || out_r >= author_num) return;   // outside returned slice

    int c = col_idx[edge];
    float th = theta[c];
    float decay = __expf(interval[edge] * th);

    const float4 e = *reinterpret_cast<const float4*>(&emb[(size_t)c * DIM + lane * 4]);
    float* o = &out[(size_t)out_r * DIM + lane * 4];
    atomicAdd(o + 0, decay * e.x);
    atomicAdd(o + 1, decay * e.y);
    atomicAdd(o + 2, decay * e.z);
    atomicAdd(o + 3, decay * e.w);
}

extern "C" void kernel_launch(void* const* d_in, const int* in_sizes, int n_in,
                              void* d_out, int out_size, void* d_ws, size_t ws_size,
                              hipStream_t stream) {
    const float* interval = (const float*)d_in[0];
    const float* emb      = (const float*)d_in[1];
    const float* params   = (const float*)d_in[2];
    const int*   eidx     = (const int*)d_in[3];   // int32 on device (harness converts)
    float* out = (float*)d_out;

    int n_edges    = in_sizes[0];
    int n_nodes    = in_sizes[1] / DIM;
    int author_num = out_size / DIM;          // 40000

    float* theta = (float*)d_ws;              // n_nodes floats

    // Zero output (harness poisons with 0xAA and does not re-poison).
    hipMemsetAsync(d_out, 0, (size_t)out_size * sizeof(float), stream);

    const int tb = 256;
    int theta_blocks = (n_nodes * 64 + tb - 1) / tb;
    theta_kernel<<<theta_blocks, tb, 0, stream>>>(emb, params, theta, n_nodes);

    long long total = (long long)n_edges * 32;
    int sb = (int)((total + tb - 1) / tb);
    scatter_kernel<<<sb, tb, 0, stream>>>(interval, emb, eidx, eidx + n_edges,
                                          theta, out, n_edges, author_num);
}

// Round 3
// 95.693 us; speedup vs baseline: 8.5995x; 8.5995x over previous
//
#include <hip/hip_runtime.h>

#define DIM  128
#define META 5000
#define CAP  64   // max edges kept per output row (Poisson(12) -> P(>64) ~ 1e-26)

// theta[n] = dot(embedding[n,:], params[:,0]); one 64-lane wave per node.
__global__ void theta_kernel(const float* __restrict__ emb,
                             const float* __restrict__ params,
                             float* __restrict__ theta, int n_nodes) {
    int gid  = blockIdx.x * blockDim.x + threadIdx.x;
    int node = gid >> 6;
    int lane = threadIdx.x & 63;
    if (node >= n_nodes) return;
    const float2 e = *reinterpret_cast<const float2*>(&emb[(size_t)node * DIM + lane * 2]);
    const float2 p = *reinterpret_cast<const float2*>(&params[lane * 2]);
    float v = e.x * p.x + e.y * p.y;
    #pragma unroll
    for (int off = 32; off; off >>= 1) v += __shfl_xor(v, off);
    if (lane == 0) theta[node] = v;
}

// Bucket edges by output row (row - META in [0, author_num)).
__global__ void fill_kernel(const int* __restrict__ row_idx,
                            int* __restrict__ counts,
                            int* __restrict__ buckets,
                            int n_edges, int author_num) {
    int e = blockIdx.x * blockDim.x + threadIdx.x;
    if (e >= n_edges) return;
    int r = row_idx[e] - META;
    if (r < 0 || r >= author_num) return;
    int slot = atomicAdd(&counts[r], 1);
    if (slot < CAP) buckets[(size_t)r * CAP + slot] = e;
}

// One wave per output row: gather + accumulate in registers, single write.
__global__ void gather_kernel(const float* __restrict__ interval,
                              const float* __restrict__ emb,
                              const int* __restrict__ col_idx,
                              const float* __restrict__ theta,
                              const int* __restrict__ counts,
                              const int* __restrict__ buckets,
                              float* __restrict__ out, int author_num) {
    int wid  = (blockIdx.x * blockDim.x + threadIdx.x) >> 6;   // = output row
    int lane = threadIdx.x & 63;
    if (wid >= author_num) return;

    int deg = counts[wid];
    if (deg > CAP) deg = CAP;

    // Lane-parallel prefetch: lane d owns edge d of this row.
    float decay = 0.f;
    int   c     = 0;
    if (lane < deg) {
        int e = buckets[(size_t)wid * CAP + lane];
        c     = col_idx[e];
        decay = __expf(interval[e] * theta[c]);
    }

    float2 acc = {0.f, 0.f};
    for (int d = 0; d < deg; ++d) {            // deg is wave-uniform
        float dd = __shfl(decay, d);
        int   cd = __shfl(c, d);
        const float2 ev = *reinterpret_cast<const float2*>(&emb[(size_t)cd * DIM + lane * 2]);
        acc.x += dd * ev.x;
        acc.y += dd * ev.y;
    }
    *reinterpret_cast<float2*>(&out[(size_t)wid * DIM + lane * 2]) = acc;
}

extern "C" void kernel_launch(void* const* d_in, const int* in_sizes, int n_in,
                              void* d_out, int out_size, void* d_ws, size_t ws_size,
                              hipStream_t stream) {
    const float* interval = (const float*)d_in[0];
    const float* emb      = (const float*)d_in[1];
    const float* params   = (const float*)d_in[2];
    const int*   eidx     = (const int*)d_in[3];   // int32 on device
    float* out = (float*)d_out;

    int n_edges    = in_sizes[0];
    int n_nodes    = in_sizes[1] / DIM;
    int author_num = out_size / DIM;               // 40000

    // workspace layout (aligned to 256B)
    char* ws = (char*)d_ws;
    float* theta   = (float*)ws;                                   // n_nodes f32
    size_t off     = ((size_t)n_nodes * 4 + 255) & ~(size_t)255;
    int*   counts  = (int*)(ws + off);                             // author_num i32
    off           += ((size_t)author_num * 4 + 255) & ~(size_t)255;
    int*   buckets = (int*)(ws + off);                             // author_num*CAP i32

    hipMemsetAsync(counts, 0, (size_t)author_num * sizeof(int), stream);

    const int tb = 256;
    theta_kernel<<<(n_nodes * 64 + tb - 1) / tb, tb, 0, stream>>>(emb, params, theta, n_nodes);
    fill_kernel<<<(n_edges + tb - 1) / tb, tb, 0, stream>>>(eidx, counts, buckets,
                                                            n_edges, author_num);
    long long gthreads = (long long)author_num * 64;
    gather_kernel<<<(int)((gthreads + tb - 1) / tb), tb, 0, stream>>>(
        interval, emb, eidx + n_edges, theta, counts, buckets, out, author_num);
}

// Round 4
// 82.078 us; speedup vs baseline: 10.0261x; 1.1659x over previous
//
#include <hip/hip_runtime.h>

#define DIM  128
#define META 5000
#define CAPP 48   // packed path: P(Poisson(12) > 48) ~ 3e-15 -> no overflow
#define CAPB 64   // fallback int-bucket path (round-3 proven)

__device__ __forceinline__ ushort f2bf(float f) {   // f32 -> bf16 (RNE)
    unsigned u = __float_as_uint(f);
    unsigned r = (u + 0x7FFFu + ((u >> 16) & 1u)) >> 16;
    return (ushort)r;
}
__device__ __forceinline__ float bf2f(ushort h) {
    return __uint_as_float(((unsigned)h) << 16);
}

// theta[n] = dot(emb[n,:], params); optionally also emit bf16 copy of emb.
__global__ void theta_cvt_kernel(const float* __restrict__ emb,
                                 const float* __restrict__ params,
                                 float* __restrict__ theta,
                                 ushort* __restrict__ embh,   // may be null
                                 int n_nodes) {
    int gid  = blockIdx.x * blockDim.x + threadIdx.x;
    int node = gid >> 6;
    int lane = threadIdx.x & 63;
    if (node >= n_nodes) return;
    const float2 e = *reinterpret_cast<const float2*>(&emb[(size_t)node * DIM + lane * 2]);
    if (embh) {
        ushort2 h; h.x = f2bf(e.x); h.y = f2bf(e.y);
        *reinterpret_cast<ushort2*>(&embh[(size_t)node * DIM + lane * 2]) = h;
    }
    const float2 p = *reinterpret_cast<const float2*>(&params[lane * 2]);
    float v = e.x * p.x + e.y * p.y;
    #pragma unroll
    for (int off = 32; off; off >>= 1) v += __shfl_xor(v, off);
    if (lane == 0) theta[node] = v;
}

// Packed fill: rec = (decay_bits, col). All edge-array reads are coalesced.
__global__ void fill_packed(const int* __restrict__ row_idx,
                            const int* __restrict__ col_idx,
                            const float* __restrict__ interval,
                            const float* __restrict__ theta,
                            int* __restrict__ counts,
                            uint2* __restrict__ recs,
                            int n_edges, int author_num) {
    int e = blockIdx.x * blockDim.x + threadIdx.x;
    if (e >= n_edges) return;
    int r = row_idx[e] - META;
    if (r < 0 || r >= author_num) return;
    int c = col_idx[e];
    float decay = __expf(interval[e] * theta[c]);
    int slot = atomicAdd(&counts[r], 1);
    if (slot < CAPP)
        recs[(size_t)r * CAPP + slot] = make_uint2(__float_as_uint(decay), (unsigned)c);
}

// One wave per row; only contiguous record read + emb gather remain.
template <int USE_BF16>
__global__ void gather_packed(const float* __restrict__ emb,
                              const ushort* __restrict__ embh,
                              const int* __restrict__ counts,
                              const uint2* __restrict__ recs,
                              float* __restrict__ out, int author_num) {
    int wid  = (blockIdx.x * blockDim.x + threadIdx.x) >> 6;
    int lane = threadIdx.x & 63;
    if (wid >= author_num) return;

    int deg = counts[wid];
    if (deg > CAPP) deg = CAPP;

    float decay = 0.f; int c = 0;
    if (lane < deg) {
        uint2 rc = recs[(size_t)wid * CAPP + lane];
        decay = __uint_as_float(rc.x);
        c     = (int)rc.y;
    }

    float2 acc = {0.f, 0.f};
    for (int d = 0; d < deg; ++d) {          // deg is wave-uniform
        float dd = __shfl(decay, d);
        int   cd = __shfl(c, d);
        float2 ev;
        if (USE_BF16) {
            ushort2 h = *reinterpret_cast<const ushort2*>(&embh[(size_t)cd * DIM + lane * 2]);
            ev.x = bf2f(h.x); ev.y = bf2f(h.y);
        } else {
            ev = *reinterpret_cast<const float2*>(&emb[(size_t)cd * DIM + lane * 2]);
        }
        acc.x += dd * ev.x;
        acc.y += dd * ev.y;
    }
    *reinterpret_cast<float2*>(&out[(size_t)wid * DIM + lane * 2]) = acc;
}

// ---- round-3 proven fallback (int buckets, fp32, per-edge loads in gather) ----
__global__ void fill_basic(const int* __restrict__ row_idx,
                           int* __restrict__ counts, int* __restrict__ buckets,
                           int n_edges, int author_num) {
    int e = blockIdx.x * blockDim.x + threadIdx.x;
    if (e >= n_edges) return;
    int r = row_idx[e] - META;
    if (r < 0 || r >= author_num) return;
    int slot = atomicAdd(&counts[r], 1);
    if (slot < CAPB) buckets[(size_t)r * CAPB + slot] = e;
}

__global__ void gather_basic(const float* __restrict__ interval,
                             const float* __restrict__ emb,
                             const int* __restrict__ col_idx,
                             const float* __restrict__ theta,
                             const int* __restrict__ counts,
                             const int* __restrict__ buckets,
                             float* __restrict__ out, int author_num) {
    int wid  = (blockIdx.x * blockDim.x + threadIdx.x) >> 6;
    int lane = threadIdx.x & 63;
    if (wid >= author_num) return;
    int deg = counts[wid]; if (deg > CAPB) deg = CAPB;
    float decay = 0.f; int c = 0;
    if (lane < deg) {
        int e = buckets[(size_t)wid * CAPB + lane];
        c     = col_idx[e];
        decay = __expf(interval[e] * theta[c]);
    }
    float2 acc = {0.f, 0.f};
    for (int d = 0; d < deg; ++d) {
        float dd = __shfl(decay, d);
        int   cd = __shfl(c, d);
        const float2 ev = *reinterpret_cast<const float2*>(&emb[(size_t)cd * DIM + lane * 2]);
        acc.x += dd * ev.x; acc.y += dd * ev.y;
    }
    *reinterpret_cast<float2*>(&out[(size_t)wid * DIM + lane * 2]) = acc;
}

static inline size_t a256(size_t x) { return (x + 255) & ~(size_t)255; }

extern "C" void kernel_launch(void* const* d_in, const int* in_sizes, int n_in,
                              void* d_out, int out_size, void* d_ws, size_t ws_size,
                              hipStream_t stream) {
    const float* interval = (const float*)d_in[0];
    const float* emb      = (const float*)d_in[1];
    const float* params   = (const float*)d_in[2];
    const int*   eidx     = (const int*)d_in[3];   // int32 on device
    float* out = (float*)d_out;

    int n_edges    = in_sizes[0];
    int n_nodes    = in_sizes[1] / DIM;
    int author_num = out_size / DIM;               // 40000

    const int* row_idx = eidx;
    const int* col_idx = eidx + n_edges;

    size_t sz_theta  = a256((size_t)n_nodes * 4);
    size_t sz_counts = a256((size_t)author_num * 4);
    size_t sz_recs   = a256((size_t)author_num * CAPP * 8);
    size_t sz_embh   = a256((size_t)n_nodes * DIM * 2);
    size_t sz_bktb   = a256((size_t)author_num * CAPB * 4);

    char* ws = (char*)d_ws;
    float* theta  = (float*)ws;
    int*   counts = (int*)(ws + sz_theta);
    char*  rest   = ws + sz_theta + sz_counts;
    size_t avail  = ws_size - (sz_theta + sz_counts);

    const int tb = 256;
    int theta_blocks  = (n_nodes * 64 + tb - 1) / tb;
    int fill_blocks   = (n_edges + tb - 1) / tb;
    int gather_blocks = (int)(((long long)author_num * 64 + tb - 1) / tb);

    hipMemsetAsync(counts, 0, (size_t)author_num * sizeof(int), stream);

    if (avail >= sz_recs + sz_embh) {
        // Tier 1: packed records + bf16 embedding
        uint2*  recs = (uint2*)rest;
        ushort* embh = (ushort*)(rest + sz_recs);
        theta_cvt_kernel<<<theta_blocks, tb, 0, stream>>>(emb, params, theta, embh, n_nodes);
        fill_packed<<<fill_blocks, tb, 0, stream>>>(row_idx, col_idx, interval, theta,
                                                    counts, recs, n_edges, author_num);
        gather_packed<1><<<gather_blocks, tb, 0, stream>>>(emb, embh, counts, recs,
                                                           out, author_num);
    } else if (avail >= sz_recs) {
        // Tier 2: packed records, fp32 embedding
        uint2* recs = (uint2*)rest;
        theta_cvt_kernel<<<theta_blocks, tb, 0, stream>>>(emb, params, theta, nullptr, n_nodes);
        fill_packed<<<fill_blocks, tb, 0, stream>>>(row_idx, col_idx, interval, theta,
                                                    counts, recs, n_edges, author_num);
        gather_packed<0><<<gather_blocks, tb, 0, stream>>>(emb, nullptr, counts, recs,
                                                           out, author_num);
    } else {
        // Tier 3: round-3 proven path
        int* buckets = (int*)rest;
        theta_cvt_kernel<<<theta_blocks, tb, 0, stream>>>(emb, params, theta, nullptr, n_nodes);
        fill_basic<<<fill_blocks, tb, 0, stream>>>(row_idx, counts, buckets,
                                                   n_edges, author_num);
        gather_basic<<<gather_blocks, tb, 0, stream>>>(interval, emb, col_idx, theta,
                                                       counts, buckets, out, author_num);
    }
}

// Round 5
// 76.767 us; speedup vs baseline: 10.7197x; 1.0692x over previous
//
#include <hip/hip_runtime.h>

#define DIM  128
#define META 5000
#define CAPP 48   // packed path: P(Poisson(12) > 48) ~ 3e-15 -> no overflow
#define CAPB 64   // fallback int-bucket path

__device__ __forceinline__ ushort f2bf(float f) {   // f32 -> bf16 (RNE)
    unsigned u = __float_as_uint(f);
    unsigned r = (u + 0x7FFFu + ((u >> 16) & 1u)) >> 16;
    return (ushort)r;
}
__device__ __forceinline__ float bf2f(ushort h) {
    return __uint_as_float(((unsigned)h) << 16);
}

// theta[n] = dot(emb[n,:], params); also zeroes counts[] (replaces the
// pathological 43us hipMemsetAsync fill kernel) and optionally emits bf16 emb.
__global__ void theta_cvt_kernel(const float* __restrict__ emb,
                                 const float* __restrict__ params,
                                 float* __restrict__ theta,
                                 ushort* __restrict__ embh,   // may be null
                                 int* __restrict__ counts,
                                 int n_nodes, int author_num) {
    int gid  = blockIdx.x * blockDim.x + threadIdx.x;
    if (gid < author_num) counts[gid] = 0;     // 3.2M threads >> 40k counters
    int node = gid >> 6;
    int lane = threadIdx.x & 63;
    if (node >= n_nodes) return;
    const float2 e = *reinterpret_cast<const float2*>(&emb[(size_t)node * DIM + lane * 2]);
    if (embh) {
        ushort2 h; h.x = f2bf(e.x); h.y = f2bf(e.y);
        *reinterpret_cast<ushort2*>(&embh[(size_t)node * DIM + lane * 2]) = h;
    }
    const float2 p = *reinterpret_cast<const float2*>(&params[lane * 2]);
    float v = e.x * p.x + e.y * p.y;
    #pragma unroll
    for (int off = 32; off; off >>= 1) v += __shfl_xor(v, off);
    if (lane == 0) theta[node] = v;
}

// Packed fill: rec = (decay_bits, col). All edge-array reads are coalesced.
__global__ void fill_packed(const int* __restrict__ row_idx,
                            const int* __restrict__ col_idx,
                            const float* __restrict__ interval,
                            const float* __restrict__ theta,
                            int* __restrict__ counts,
                            uint2* __restrict__ recs,
                            int n_edges, int author_num) {
    int e = blockIdx.x * blockDim.x + threadIdx.x;
    if (e >= n_edges) return;
    int r = row_idx[e] - META;
    if (r < 0 || r >= author_num) return;
    int c = col_idx[e];
    float decay = __expf(interval[e] * theta[c]);
    int slot = atomicAdd(&counts[r], 1);
    if (slot < CAPP)
        recs[(size_t)r * CAPP + slot] = make_uint2(__float_as_uint(decay), (unsigned)c);
}

// One wave per row; only contiguous record read + emb gather remain.
template <int USE_BF16>
__global__ void gather_packed(const float* __restrict__ emb,
                              const ushort* __restrict__ embh,
                              const int* __restrict__ counts,
                              const uint2* __restrict__ recs,
                              float* __restrict__ out, int author_num) {
    int wid  = (blockIdx.x * blockDim.x + threadIdx.x) >> 6;
    int lane = threadIdx.x & 63;
    if (wid >= author_num) return;

    int deg = counts[wid];
    if (deg > CAPP) deg = CAPP;

    float decay = 0.f; int c = 0;
    if (lane < deg) {
        uint2 rc = recs[(size_t)wid * CAPP + lane];
        decay = __uint_as_float(rc.x);
        c     = (int)rc.y;
    }

    float2 acc = {0.f, 0.f};
    for (int d = 0; d < deg; ++d) {          // deg is wave-uniform
        float dd = __shfl(decay, d);
        int   cd = __shfl(c, d);
        float2 ev;
        if (USE_BF16) {
            ushort2 h = *reinterpret_cast<const ushort2*>(&embh[(size_t)cd * DIM + lane * 2]);
            ev.x = bf2f(h.x); ev.y = bf2f(h.y);
        } else {
            ev = *reinterpret_cast<const float2*>(&emb[(size_t)cd * DIM + lane * 2]);
        }
        acc.x += dd * ev.x;
        acc.y += dd * ev.y;
    }
    *reinterpret_cast<float2*>(&out[(size_t)wid * DIM + lane * 2]) = acc;
}

// ---- fallback (int buckets, fp32, per-edge loads in gather) ----
__global__ void fill_basic(const int* __restrict__ row_idx,
                           int* __restrict__ counts, int* __restrict__ buckets,
                           int n_edges, int author_num) {
    int e = blockIdx.x * blockDim.x + threadIdx.x;
    if (e >= n_edges) return;
    int r = row_idx[e] - META;
    if (r < 0 || r >= author_num) return;
    int slot = atomicAdd(&counts[r], 1);
    if (slot < CAPB) buckets[(size_t)r * CAPB + slot] = e;
}

__global__ void gather_basic(const float* __restrict__ interval,
                             const float* __restrict__ emb,
                             const int* __restrict__ col_idx,
                             const float* __restrict__ theta,
                             const int* __restrict__ counts,
                             const int* __restrict__ buckets,
                             float* __restrict__ out, int author_num) {
    int wid  = (blockIdx.x * blockDim.x + threadIdx.x) >> 6;
    int lane = threadIdx.x & 63;
    if (wid >= author_num) return;
    int deg = counts[wid]; if (deg > CAPB) deg = CAPB;
    float decay = 0.f; int c = 0;
    if (lane < deg) {
        int e = buckets[(size_t)wid * CAPB + lane];
        c     = col_idx[e];
        decay = __expf(interval[e] * theta[c]);
    }
    float2 acc = {0.f, 0.f};
    for (int d = 0; d < deg; ++d) {
        float dd = __shfl(decay, d);
        int   cd = __shfl(c, d);
        const float2 ev = *reinterpret_cast<const float2*>(&emb[(size_t)cd * DIM + lane * 2]);
        acc.x += dd * ev.x; acc.y += dd * ev.y;
    }
    *reinterpret_cast<float2*>(&out[(size_t)wid * DIM + lane * 2]) = acc;
}

static inline size_t a256(size_t x) { return (x + 255) & ~(size_t)255; }

extern "C" void kernel_launch(void* const* d_in, const int* in_sizes, int n_in,
                              void* d_out, int out_size, void* d_ws, size_t ws_size,
                              hipStream_t stream) {
    const float* interval = (const float*)d_in[0];
    const float* emb      = (const float*)d_in[1];
    const float* params   = (const float*)d_in[2];
    const int*   eidx     = (const int*)d_in[3];   // int32 on device
    float* out = (float*)d_out;

    int n_edges    = in_sizes[0];
    int n_nodes    = in_sizes[1] / DIM;
    int author_num = out_size / DIM;               // 40000

    const int* row_idx = eidx;
    const int* col_idx = eidx + n_edges;

    size_t sz_theta  = a256((size_t)n_nodes * 4);
    size_t sz_counts = a256((size_t)author_num * 4);
    size_t sz_recs   = a256((size_t)author_num * CAPP * 8);
    size_t sz_embh   = a256((size_t)n_nodes * DIM * 2);

    char* ws = (char*)d_ws;
    float* theta  = (float*)ws;
    int*   counts = (int*)(ws + sz_theta);
    char*  rest   = ws + sz_theta + sz_counts;
    size_t avail  = ws_size - (sz_theta + sz_counts);

    const int tb = 256;
    int theta_blocks  = (n_nodes * 64 + tb - 1) / tb;
    int fill_blocks   = (n_edges + tb - 1) / tb;
    int gather_blocks = (int)(((long long)author_num * 64 + tb - 1) / tb);

    if (avail >= sz_recs + sz_embh) {
        // Tier 1: packed records + bf16 embedding
        uint2*  recs = (uint2*)rest;
        ushort* embh = (ushort*)(rest + sz_recs);
        theta_cvt_kernel<<<theta_blocks, tb, 0, stream>>>(emb, params, theta, embh,
                                                          counts, n_nodes, author_num);
        fill_packed<<<fill_blocks, tb, 0, stream>>>(row_idx, col_idx, interval, theta,
                                                    counts, recs, n_edges, author_num);
        gather_packed<1><<<gather_blocks, tb, 0, stream>>>(emb, embh, counts, recs,
                                                           out, author_num);
    } else if (avail >= sz_recs) {
        // Tier 2: packed records, fp32 embedding
        uint2* recs = (uint2*)rest;
        theta_cvt_kernel<<<theta_blocks, tb, 0, stream>>>(emb, params, theta, nullptr,
                                                          counts, n_nodes, author_num);
        fill_packed<<<fill_blocks, tb, 0, stream>>>(row_idx, col_idx, interval, theta,
                                                    counts, recs, n_edges, author_num);
        gather_packed<0><<<gather_blocks, tb, 0, stream>>>(emb, nullptr, counts, recs,
                                                           out, author_num);
    } else {
        // Tier 3: basic path
        int* buckets = (int*)rest;
        theta_cvt_kernel<<<theta_blocks, tb, 0, stream>>>(emb, params, theta, nullptr,
                                                          counts, n_nodes, author_num);
        fill_basic<<<fill_blocks, tb, 0, stream>>>(row_idx, counts, buckets,
                                                   n_edges, author_num);
        gather_basic<<<gather_blocks, tb, 0, stream>>>(interval, emb, col_idx, theta,
                                                       counts, buckets, out, author_num);
    }
}

// Round 6
// 62.397 us; speedup vs baseline: 13.1884x; 1.2303x over previous
//
#include <hip/hip_runtime.h>

#define DIM  128
#define META 5000
#define CAPP 48   // packed path: P(Poisson(12) > 48) ~ 3e-15 -> no overflow
#define CAPB 64   // fallback int-bucket path

__device__ __forceinline__ ushort f2bf(float f) {   // f32 -> bf16 (RNE)
    unsigned u = __float_as_uint(f);
    unsigned r = (u + 0x7FFFu + ((u >> 16) & 1u)) >> 16;
    return (ushort)r;
}
__device__ __forceinline__ float bf2f(ushort h) {
    return __uint_as_float(((unsigned)h) << 16);
}

// theta[n] = dot(emb[n,:], params); also zeroes counts[] and emits bf16 emb.
__global__ void theta_cvt_kernel(const float* __restrict__ emb,
                                 const float* __restrict__ params,
                                 float* __restrict__ theta,
                                 ushort* __restrict__ embh,   // may be null
                                 int* __restrict__ counts,
                                 int n_nodes, int author_num) {
    int gid  = blockIdx.x * blockDim.x + threadIdx.x;
    if (gid < author_num) counts[gid] = 0;     // 3.2M threads >> 40k counters
    int node = gid >> 6;
    int lane = threadIdx.x & 63;
    if (node >= n_nodes) return;
    const float2 e = *reinterpret_cast<const float2*>(&emb[(size_t)node * DIM + lane * 2]);
    if (embh) {
        ushort2 h; h.x = f2bf(e.x); h.y = f2bf(e.y);
        *reinterpret_cast<ushort2*>(&embh[(size_t)node * DIM + lane * 2]) = h;
    }
    const float2 p = *reinterpret_cast<const float2*>(&params[lane * 2]);
    float v = e.x * p.x + e.y * p.y;
    #pragma unroll
    for (int off = 32; off; off >>= 1) v += __shfl_xor(v, off);
    if (lane == 0) theta[node] = v;
}

// Packed fill: rec = (decay_bits, col). All edge-array reads are coalesced.
__global__ void fill_packed(const int* __restrict__ row_idx,
                            const int* __restrict__ col_idx,
                            const float* __restrict__ interval,
                            const float* __restrict__ theta,
                            int* __restrict__ counts,
                            uint2* __restrict__ recs,
                            int n_edges, int author_num) {
    int e = blockIdx.x * blockDim.x + threadIdx.x;
    if (e >= n_edges) return;
    int r = row_idx[e] - META;
    if (r < 0 || r >= author_num) return;
    int c = col_idx[e];
    float decay = __expf(interval[e] * theta[c]);
    int slot = atomicAdd(&counts[r], 1);
    if (slot < CAPP)
        recs[(size_t)r * CAPP + slot] = make_uint2(__float_as_uint(decay), (unsigned)c);
}

// One wave per row. Half-wave h (lanes h*32..h*32+31) handles edge d+h;
// each lane loads ushort4 (4 dims). Unrolled to 4 edges/iter for ILP.
__global__ void gather_packed2(const ushort* __restrict__ embh,
                               const int* __restrict__ counts,
                               const uint2* __restrict__ recs,
                               float* __restrict__ out, int author_num) {
    int wid  = (blockIdx.x * blockDim.x + threadIdx.x) >> 6;
    int lane = threadIdx.x & 63;
    if (wid >= author_num) return;
    int half = lane >> 5;
    int l32  = lane & 31;

    int deg = counts[wid];
    if (deg > CAPP) deg = CAPP;

    float decay = 0.f; int c = 0;
    if (lane < deg) {
        uint2 rc = recs[(size_t)wid * CAPP + lane];
        decay = __uint_as_float(rc.x);
        c     = (int)rc.y;
    }

    float4 acc = {0.f, 0.f, 0.f, 0.f};
    int d = 0;
    // 4 edges per iteration: this half-wave covers edges d+2*half, d+2*half+1.
    for (; d + 4 <= deg; d += 4) {
        int e0 = d + half * 2, e1 = e0 + 1;
        float d0 = __shfl(decay, e0);
        float d1 = __shfl(decay, e1);
        int   c0 = __shfl(c, e0);
        int   c1 = __shfl(c, e1);
        ushort4 h0 = *reinterpret_cast<const ushort4*>(&embh[(size_t)c0 * DIM + l32 * 4]);
        ushort4 h1 = *reinterpret_cast<const ushort4*>(&embh[(size_t)c1 * DIM + l32 * 4]);
        acc.x += d0 * bf2f(h0.x); acc.y += d0 * bf2f(h0.y);
        acc.z += d0 * bf2f(h0.z); acc.w += d0 * bf2f(h0.w);
        acc.x += d1 * bf2f(h1.x); acc.y += d1 * bf2f(h1.y);
        acc.z += d1 * bf2f(h1.z); acc.w += d1 * bf2f(h1.w);
    }
    // 2 edges: half h covers edge d+h.
    for (; d + 2 <= deg; d += 2) {
        int e0 = d + half;
        float d0 = __shfl(decay, e0);
        int   c0 = __shfl(c, e0);
        ushort4 h0 = *reinterpret_cast<const ushort4*>(&embh[(size_t)c0 * DIM + l32 * 4]);
        acc.x += d0 * bf2f(h0.x); acc.y += d0 * bf2f(h0.y);
        acc.z += d0 * bf2f(h0.z); acc.w += d0 * bf2f(h0.w);
    }
    // last odd edge: both halves load it, half 1 contributes zero.
    if (d < deg) {
        float d0 = __shfl(decay, d);
        int   c0 = __shfl(c, d);
        d0 = half ? 0.f : d0;
        ushort4 h0 = *reinterpret_cast<const ushort4*>(&embh[(size_t)c0 * DIM + l32 * 4]);
        acc.x += d0 * bf2f(h0.x); acc.y += d0 * bf2f(h0.y);
        acc.z += d0 * bf2f(h0.z); acc.w += d0 * bf2f(h0.w);
    }

    // combine halves: lane L (<32) needs half-1's acc from lane L+32.
    acc.x += __shfl_xor(acc.x, 32);
    acc.y += __shfl_xor(acc.y, 32);
    acc.z += __shfl_xor(acc.z, 32);
    acc.w += __shfl_xor(acc.w, 32);
    if (half == 0) {
        __builtin_nontemporal_store(acc.x, &out[(size_t)wid * DIM + l32 * 4 + 0]);
        __builtin_nontemporal_store(acc.y, &out[(size_t)wid * DIM + l32 * 4 + 1]);
        __builtin_nontemporal_store(acc.z, &out[(size_t)wid * DIM + l32 * 4 + 2]);
        __builtin_nontemporal_store(acc.w, &out[(size_t)wid * DIM + l32 * 4 + 3]);
    }
}

// ---- fallback (int buckets, fp32, per-edge loads in gather) ----
__global__ void fill_basic(const int* __restrict__ row_idx,
                           int* __restrict__ counts, int* __restrict__ buckets,
                           int n_edges, int author_num) {
    int e = blockIdx.x * blockDim.x + threadIdx.x;
    if (e >= n_edges) return;
    int r = row_idx[e] - META;
    if (r < 0 || r >= author_num) return;
    int slot = atomicAdd(&counts[r], 1);
    if (slot < CAPB) buckets[(size_t)r * CAPB + slot] = e;
}

__global__ void gather_basic(const float* __restrict__ interval,
                             const float* __restrict__ emb,
                             const int* __restrict__ col_idx,
                             const float* __restrict__ theta,
                             const int* __restrict__ counts,
                             const int* __restrict__ buckets,
                             float* __restrict__ out, int author_num) {
    int wid  = (blockIdx.x * blockDim.x + threadIdx.x) >> 6;
    int lane = threadIdx.x & 63;
    if (wid >= author_num) return;
    int deg = counts[wid]; if (deg > CAPB) deg = CAPB;
    float decay = 0.f; int c = 0;
    if (lane < deg) {
        int e = buckets[(size_t)wid * CAPB + lane];
        c     = col_idx[e];
        decay = __expf(interval[e] * theta[c]);
    }
    float2 acc = {0.f, 0.f};
    for (int d = 0; d < deg; ++d) {
        float dd = __shfl(decay, d);
        int   cd = __shfl(c, d);
        const float2 ev = *reinterpret_cast<const float2*>(&emb[(size_t)cd * DIM + lane * 2]);
        acc.x += dd * ev.x; acc.y += dd * ev.y;
    }
    *reinterpret_cast<float2*>(&out[(size_t)wid * DIM + lane * 2]) = acc;
}

static inline size_t a256(size_t x) { return (x + 255) & ~(size_t)255; }

extern "C" void kernel_launch(void* const* d_in, const int* in_sizes, int n_in,
                              void* d_out, int out_size, void* d_ws, size_t ws_size,
                              hipStream_t stream) {
    const float* interval = (const float*)d_in[0];
    const float* emb      = (const float*)d_in[1];
    const float* params   = (const float*)d_in[2];
    const int*   eidx     = (const int*)d_in[3];   // int32 on device
    float* out = (float*)d_out;

    int n_edges    = in_sizes[0];
    int n_nodes    = in_sizes[1] / DIM;
    int author_num = out_size / DIM;               // 40000

    const int* row_idx = eidx;
    const int* col_idx = eidx + n_edges;

    size_t sz_theta  = a256((size_t)n_nodes * 4);
    size_t sz_counts = a256((size_t)author_num * 4);
    size_t sz_recs   = a256((size_t)author_num * CAPP * 8);
    size_t sz_embh   = a256((size_t)n_nodes * DIM * 2);

    char* ws = (char*)d_ws;
    float* theta  = (float*)ws;
    int*   counts = (int*)(ws + sz_theta);
    char*  rest   = ws + sz_theta + sz_counts;
    size_t avail  = ws_size - (sz_theta + sz_counts);

    const int tb = 256;
    int theta_blocks  = (n_nodes * 64 + tb - 1) / tb;
    int fill_blocks   = (n_edges + tb - 1) / tb;
    int gather_blocks = (int)(((long long)author_num * 64 + tb - 1) / tb);

    if (avail >= sz_recs + sz_embh) {
        // Tier 1: packed records + bf16 embedding
        uint2*  recs = (uint2*)rest;
        ushort* embh = (ushort*)(rest + sz_recs);
        theta_cvt_kernel<<<theta_blocks, tb, 0, stream>>>(emb, params, theta, embh,
                                                          counts, n_nodes, author_num);
        fill_packed<<<fill_blocks, tb, 0, stream>>>(row_idx, col_idx, interval, theta,
                                                    counts, recs, n_edges, author_num);
        gather_packed2<<<gather_blocks, tb, 0, stream>>>(embh, counts, recs,
                                                         out, author_num);
    } else {
        // Fallback: basic path (fp32, int buckets)
        int* buckets = (int*)rest;
        theta_cvt_kernel<<<theta_blocks, tb, 0, stream>>>(emb, params, theta, nullptr,
                                                          counts, n_nodes, author_num);
        fill_basic<<<fill_blocks, tb, 0, stream>>>(row_idx, counts, buckets,
                                                   n_edges, author_num);
        gather_basic<<<gather_blocks, tb, 0, stream>>>(interval, emb, col_idx, theta,
                                                       counts, buckets, out, author_num);
    }
}

// Round 8
// 59.106 us; speedup vs baseline: 13.9227x; 1.0557x over previous
//
#include <hip/hip_runtime.h>

#define DIM  128
#define META 5000
#define CAPP 48   // packed records per row: P(Poisson(12) > 48) ~ 3e-15
#define CAPB 64   // fallback path

typedef float f32x4 __attribute__((ext_vector_type(4)));  // native vec for NT store

__device__ __forceinline__ ushort f2bf(float f) {   // f32 -> bf16 (RNE)
    unsigned u = __float_as_uint(f);
    unsigned r = (u + 0x7FFFu + ((u >> 16) & 1u)) >> 16;
    return (ushort)r;
}
__device__ __forceinline__ float bf_lo(unsigned u) { return __uint_as_float(u << 16); }
__device__ __forceinline__ float bf_hi(unsigned u) { return __uint_as_float(u & 0xFFFF0000u); }

// theta[n] = dot(emb[n,:], params); zeroes counts[]; emits bf16 emb.
// One wave handles 2 nodes: half-wave h -> node 2*wid+h, lane loads float4.
__global__ void theta_cvt_kernel(const float* __restrict__ emb,
                                 const float* __restrict__ params,
                                 float* __restrict__ theta,
                                 ushort* __restrict__ embh,   // may be null
                                 int* __restrict__ counts,
                                 int n_nodes, int author_num) {
    int gid  = blockIdx.x * blockDim.x + threadIdx.x;
    if (gid < author_num) counts[gid] = 0;     // grid >> 40k counters
    int wid  = gid >> 6;
    int lane = threadIdx.x & 63;
    int half = lane >> 5;
    int l32  = lane & 31;
    int node = wid * 2 + half;
    if (node >= n_nodes) return;

    const float4 e = *reinterpret_cast<const float4*>(&emb[(size_t)node * DIM + l32 * 4]);
    if (embh) {
        ushort4 h; h.x = f2bf(e.x); h.y = f2bf(e.y); h.z = f2bf(e.z); h.w = f2bf(e.w);
        *reinterpret_cast<ushort4*>(&embh[(size_t)node * DIM + l32 * 4]) = h;
    }
    const float4 p = *reinterpret_cast<const float4*>(&params[l32 * 4]);
    float v = e.x * p.x + e.y * p.y + e.z * p.z + e.w * p.w;
    #pragma unroll
    for (int off = 16; off; off >>= 1) v += __shfl_xor(v, off);  // within 32-lane half
    if (l32 == 0) theta[node] = v;
}

// Packed fill: rec = (decay_bits, col). All edge-array reads coalesced.
__global__ void fill_packed(const int* __restrict__ row_idx,
                            const int* __restrict__ col_idx,
                            const float* __restrict__ interval,
                            const float* __restrict__ theta,
                            int* __restrict__ counts,
                            uint2* __restrict__ recs,
                            int n_edges, int author_num) {
    int e = blockIdx.x * blockDim.x + threadIdx.x;
    if (e >= n_edges) return;
    int r = row_idx[e] - META;
    if (r < 0 || r >= author_num) return;
    int c = col_idx[e];
    float decay = __expf(interval[e] * theta[c]);
    int slot = atomicAdd(&counts[r], 1);
    if (slot < CAPP)
        recs[(size_t)r * CAPP + slot] = make_uint2(__float_as_uint(decay), (unsigned)c);
}

// One wave per row. Quarter-wave q (16 lanes) handles one edge per step;
// each lane loads uint4 = 8 bf16 dims (16 B). 8 edges per unrolled iter.
__global__ void gather_packed3(const ushort* __restrict__ embh,
                               const int* __restrict__ counts,
                               const uint2* __restrict__ recs,
                               float* __restrict__ out, int author_num) {
    int wid  = (blockIdx.x * blockDim.x + threadIdx.x) >> 6;
    int lane = threadIdx.x & 63;
    if (wid >= author_num) return;
    int q   = lane >> 4;     // quarter 0..3
    int l16 = lane & 15;

    int deg = counts[wid];
    if (deg > CAPP) deg = CAPP;

    float decay = 0.f; int c = 0;
    if (lane < deg) {
        uint2 rc = recs[(size_t)wid * CAPP + lane];
        decay = __uint_as_float(rc.x);
        c     = (int)rc.y;
    }

    float a0=0,a1=0,a2=0,a3=0,a4=0,a5=0,a6=0,a7=0;
    int d = 0;
    // 8 edges/iter: quarter q covers edges d+2q, d+2q+1 (two independent loads).
    for (; d + 8 <= deg; d += 8) {
        int e0 = d + 2 * q, e1 = e0 + 1;
        float d0 = __shfl(decay, e0);
        float d1 = __shfl(decay, e1);
        int   c0 = __shfl(c, e0);
        int   c1 = __shfl(c, e1);
        uint4 h0 = *reinterpret_cast<const uint4*>(&embh[(size_t)c0 * DIM + l16 * 8]);
        uint4 h1 = *reinterpret_cast<const uint4*>(&embh[(size_t)c1 * DIM + l16 * 8]);
        a0 += d0 * bf_lo(h0.x); a1 += d0 * bf_hi(h0.x);
        a2 += d0 * bf_lo(h0.y); a3 += d0 * bf_hi(h0.y);
        a4 += d0 * bf_lo(h0.z); a5 += d0 * bf_hi(h0.z);
        a6 += d0 * bf_lo(h0.w); a7 += d0 * bf_hi(h0.w);
        a0 += d1 * bf_lo(h1.x); a1 += d1 * bf_hi(h1.x);
        a2 += d1 * bf_lo(h1.y); a3 += d1 * bf_hi(h1.y);
        a4 += d1 * bf_lo(h1.z); a5 += d1 * bf_hi(h1.z);
        a6 += d1 * bf_lo(h1.w); a7 += d1 * bf_hi(h1.w);
    }
    // 4 edges/iter: quarter q covers edge d+q.
    for (; d + 4 <= deg; d += 4) {
        int e0 = d + q;
        float d0 = __shfl(decay, e0);
        int   c0 = __shfl(c, e0);
        uint4 h0 = *reinterpret_cast<const uint4*>(&embh[(size_t)c0 * DIM + l16 * 8]);
        a0 += d0 * bf_lo(h0.x); a1 += d0 * bf_hi(h0.x);
        a2 += d0 * bf_lo(h0.y); a3 += d0 * bf_hi(h0.y);
        a4 += d0 * bf_lo(h0.z); a5 += d0 * bf_hi(h0.z);
        a6 += d0 * bf_lo(h0.w); a7 += d0 * bf_hi(h0.w);
    }
    // remainder 1..3: quarter q covers edge d+q if valid, else contributes 0.
    if (d < deg) {
        int e0 = d + q;
        bool v = e0 < deg;
        int  se = v ? e0 : d;
        float d0 = __shfl(decay, se);
        int   c0 = __shfl(c, se);
        d0 = v ? d0 : 0.f;
        uint4 h0 = *reinterpret_cast<const uint4*>(&embh[(size_t)c0 * DIM + l16 * 8]);
        a0 += d0 * bf_lo(h0.x); a1 += d0 * bf_hi(h0.x);
        a2 += d0 * bf_lo(h0.y); a3 += d0 * bf_hi(h0.y);
        a4 += d0 * bf_lo(h0.z); a5 += d0 * bf_hi(h0.z);
        a6 += d0 * bf_lo(h0.w); a7 += d0 * bf_hi(h0.w);
    }

    // combine quarters: fold lanes ^16 then ^32.
    a0 += __shfl_xor(a0, 16); a1 += __shfl_xor(a1, 16);
    a2 += __shfl_xor(a2, 16); a3 += __shfl_xor(a3, 16);
    a4 += __shfl_xor(a4, 16); a5 += __shfl_xor(a5, 16);
    a6 += __shfl_xor(a6, 16); a7 += __shfl_xor(a7, 16);
    a0 += __shfl_xor(a0, 32); a1 += __shfl_xor(a1, 32);
    a2 += __shfl_xor(a2, 32); a3 += __shfl_xor(a3, 32);
    a4 += __shfl_xor(a4, 32); a5 += __shfl_xor(a5, 32);
    a6 += __shfl_xor(a6, 32); a7 += __shfl_xor(a7, 32);

    if (q == 0) {     // lanes 0..15 own dims l16*8 .. l16*8+7
        float* o = &out[(size_t)wid * DIM + l16 * 8];
        f32x4 vA = {a0, a1, a2, a3};
        f32x4 vB = {a4, a5, a6, a7};
        __builtin_nontemporal_store(vA, reinterpret_cast<f32x4*>(o));
        __builtin_nontemporal_store(vB, reinterpret_cast<f32x4*>(o + 4));
    }
}

// ---- fallback (fp32, int buckets) ----
__global__ void fill_basic(const int* __restrict__ row_idx,
                           int* __restrict__ counts, int* __restrict__ buckets,
                           int n_edges, int author_num) {
    int e = blockIdx.x * blockDim.x + threadIdx.x;
    if (e >= n_edges) return;
    int r = row_idx[e] - META;
    if (r < 0 || r >= author_num) return;
    int slot = atomicAdd(&counts[r], 1);
    if (slot < CAPB) buckets[(size_t)r * CAPB + slot] = e;
}

__global__ void gather_basic(const float* __restrict__ interval,
                             const float* __restrict__ emb,
                             const int* __restrict__ col_idx,
                             const float* __restrict__ theta,
                             const int* __restrict__ counts,
                             const int* __restrict__ buckets,
                             float* __restrict__ out, int author_num) {
    int wid  = (blockIdx.x * blockDim.x + threadIdx.x) >> 6;
    int lane = threadIdx.x & 63;
    if (wid >= author_num) return;
    int deg = counts[wid]; if (deg > CAPB) deg = CAPB;
    float decay = 0.f; int c = 0;
    if (lane < deg) {
        int e = buckets[(size_t)wid * CAPB + lane];
        c     = col_idx[e];
        decay = __expf(interval[e] * theta[c]);
    }
    float2 acc = {0.f, 0.f};
    for (int d = 0; d < deg; ++d) {
        float dd = __shfl(decay, d);
        int   cd = __shfl(c, d);
        const float2 ev = *reinterpret_cast<const float2*>(&emb[(size_t)cd * DIM + lane * 2]);
        acc.x += dd * ev.x; acc.y += dd * ev.y;
    }
    *reinterpret_cast<float2*>(&out[(size_t)wid * DIM + lane * 2]) = acc;
}

static inline size_t a256(size_t x) { return (x + 255) & ~(size_t)255; }

extern "C" void kernel_launch(void* const* d_in, const int* in_sizes, int n_in,
                              void* d_out, int out_size, void* d_ws, size_t ws_size,
                              hipStream_t stream) {
    const float* interval = (const float*)d_in[0];
    const float* emb      = (const float*)d_in[1];
    const float* params   = (const float*)d_in[2];
    const int*   eidx     = (const int*)d_in[3];   // int32 on device
    float* out = (float*)d_out;

    int n_edges    = in_sizes[0];
    int n_nodes    = in_sizes[1] / DIM;
    int author_num = out_size / DIM;               // 40000

    const int* row_idx = eidx;
    const int* col_idx = eidx + n_edges;

    size_t sz_theta  = a256((size_t)n_nodes * 4);
    size_t sz_counts = a256((size_t)author_num * 4);
    size_t sz_recs   = a256((size_t)author_num * CAPP * 8);
    size_t sz_embh   = a256((size_t)n_nodes * DIM * 2);

    char* ws = (char*)d_ws;
    float* theta  = (float*)ws;
    int*   counts = (int*)(ws + sz_theta);
    char*  rest   = ws + sz_theta + sz_counts;
    size_t avail  = ws_size - (sz_theta + sz_counts);

    const int tb = 256;
    int theta_waves   = (n_nodes + 1) / 2;                    // 2 nodes/wave
    int theta_blocks  = (int)(((long long)theta_waves * 64 + tb - 1) / tb);
    int fill_blocks   = (n_edges + tb - 1) / tb;
    int gather_blocks = (int)(((long long)author_num * 64 + tb - 1) / tb);

    if (avail >= sz_recs + sz_embh) {
        // Tier 1: packed records + bf16 embedding
        uint2*  recs = (uint2*)rest;
        ushort* embh = (ushort*)(rest + sz_recs);
        theta_cvt_kernel<<<theta_blocks, tb, 0, stream>>>(emb, params, theta, embh,
                                                          counts, n_nodes, author_num);
        fill_packed<<<fill_blocks, tb, 0, stream>>>(row_idx, col_idx, interval, theta,
                                                    counts, recs, n_edges, author_num);
        gather_packed3<<<gather_blocks, tb, 0, stream>>>(embh, counts, recs,
                                                         out, author_num);
    } else {
        // Fallback: basic path (fp32, int buckets)
        int* buckets = (int*)rest;
        theta_cvt_kernel<<<theta_blocks, tb, 0, stream>>>(emb, params, theta, nullptr,
                                                          counts, n_nodes, author_num);
        fill_basic<<<fill_blocks, tb, 0, stream>>>(row_idx, counts, buckets,
                                                   n_edges, author_num);
        gather_basic<<<gather_blocks, tb, 0, stream>>>(interval, emb, col_idx, theta,
                                                       counts, buckets, out, author_num);
    }
}